// Round 10
// baseline (340.101 us; speedup 1.0000x reference)
//
#include <hip/hip_runtime.h>
#include <hip/hip_bf16.h>

// Problem shape: M = B*S = 8192, K = NX = 1024, N = NF = 4096
#define M_DIM 8192
#define K_DIM 1024
#define N_DIM 4096

typedef __attribute__((ext_vector_type(8))) short bf16x8;
typedef __attribute__((ext_vector_type(4))) int i32x4;
typedef __attribute__((ext_vector_type(8))) int i32x8;
typedef __attribute__((ext_vector_type(16))) int i32x16;
typedef __attribute__((ext_vector_type(16))) float f32x16;

__device__ __forceinline__ short f2bf(float f) {
  unsigned u = __builtin_bit_cast(unsigned, f);
  u = (u + 0x7fffu + ((u >> 16) & 1u)) >> 16;
  return (short)u;
}

// f32 -> OCP e4m3fn, exact for our value set (small ints x 2^e)
__device__ __forceinline__ unsigned f2fp8(float v) {
  unsigned b = __builtin_bit_cast(unsigned, v);
  unsigned sg = (b >> 24) & 0x80u;
  unsigned ab = b & 0x7fffffffu;
  if (ab == 0) return sg;
  int e = (int)(ab >> 23) - 127;
  unsigned m3 = (ab >> 20) & 7u;
  if (e >= -6) return sg | (unsigned)((e + 7) << 3) | m3;
  return sg | ((8u + m3) >> (-6 - e));  // subnormal (exact for our values)
}

__device__ __forceinline__ float gelu_f(float x) {
  float u = 0.7978845608028654f * (x + 0.044715f * x * x * x);
  float e = __expf(2.0f * u);
  float t = 1.0f - 2.0f / (e + 1.0f);
  return 0.5f * x * (1.0f + t);
}

__device__ __forceinline__ void gload16(const void* g, void* l) {
  __builtin_amdgcn_global_load_lds((const __attribute__((address_space(1))) void*)g,
                                   (__attribute__((address_space(3))) void*)l, 16, 0, 0);
}

// ---------------- per-k power-of-2 weight scale ----------------
__global__ void rowmax_kernel(const float* __restrict__ w, float* __restrict__ mw) {
  int row = blockIdx.x * 4 + (threadIdx.x >> 6);
  int lane = threadIdx.x & 63;
  const float4* rp = (const float4*)(w + (size_t)row * N_DIM);
  float m = 0.0f;
#pragma unroll
  for (int it = 0; it < 16; ++it) {
    float4 v = rp[it * 64 + lane];
    m = fmaxf(m, fmaxf(fmaxf(fabsf(v.x), fabsf(v.y)), fmaxf(fabsf(v.z), fabsf(v.w))));
  }
#pragma unroll
  for (int off = 32; off > 0; off >>= 1) m = fmaxf(m, __shfl_xor(m, off, 64));
  if (lane == 0) mw[row] = exp2f(rintf(log2f(m)));
}

// ---------------- prep A: one thread per (kg16, m); 16 k-values ----------------
// aqi: [kg16:64][m]x16B i8 (in_q) | adf: [kg16:64][m]x16B fp8 (deq(in_q)) | af: [kg8:128][m]x16B bf16
__global__ void prep_a_kernel(const float* __restrict__ inp, signed char* __restrict__ aqi,
                              unsigned char* __restrict__ adf, short* __restrict__ af) {
  int c = blockIdx.x * 256 + threadIdx.x;
  int kg = c >> 13, m = c & 8191;
  const float4* src = (const float4*)(inp + (size_t)m * K_DIM + kg * 16);
  float xs[16];
#pragma unroll
  for (int v = 0; v < 4; ++v) {
    float4 t = src[v];
    xs[v * 4 + 0] = t.x; xs[v * 4 + 1] = t.y; xs[v * 4 + 2] = t.z; xs[v * 4 + 3] = t.w;
  }
  int qi[4] = {0, 0, 0, 0};
  int qf[4] = {0, 0, 0, 0};
  bf16x8 b0, b1;
#pragma unroll
  for (int j = 0; j < 16; ++j) {
    float x = xs[j];
    float s = (x > 0.f) ? 1.f : ((x < 0.f) ? -1.f : 0.f);
    float r = rintf(fabsf(x));
    int iq = (int)(s * fminf(r + 1.f, 7.f));
    qi[j >> 2] |= (iq & 255) << ((j & 3) * 8);
    unsigned f8 = f2fp8(s * fminf(r, 6.f));
    qf[j >> 2] |= (int)f8 << ((j & 3) * 8);
    short bb = f2bf(x);
    if (j < 8) b0[j] = bb; else b1[j - 8] = bb;
  }
  *(i32x4*)(aqi + ((size_t)kg * M_DIM + m) * 16) = (i32x4){qi[0], qi[1], qi[2], qi[3]};
  *(i32x4*)(adf + ((size_t)kg * M_DIM + m) * 16) = (i32x4){qf[0], qf[1], qf[2], qf[3]};
  *(bf16x8*)(af + ((size_t)(2 * kg) * M_DIM + m) * 8) = b0;
  *(bf16x8*)(af + ((size_t)(2 * kg + 1) * M_DIM + m) * 8) = b1;
}

// ---------------- prep W: one thread per (kg16, n) ----------------
__global__ void prep_w_kernel(const float* __restrict__ w, const float* __restrict__ mw,
                              signed char* __restrict__ wqi, unsigned char* __restrict__ wdf,
                              short* __restrict__ wf) {
  int c = blockIdx.x * 256 + threadIdx.x;
  int kg = c >> 12, n = c & 4095;
  int qi[4] = {0, 0, 0, 0};
  int qf[4] = {0, 0, 0, 0};
  bf16x8 b0, b1;
#pragma unroll
  for (int j = 0; j < 16; ++j) {
    float wv = w[(size_t)(kg * 16 + j) * N_DIM + n];
    float sc = mw[kg * 16 + j];
    float s = (wv > 0.f) ? 1.f : ((wv < 0.f) ? -1.f : 0.f);
    float r = rintf(fabsf(wv) * (8.0f / sc));
    int iq = (int)(s * fminf(r + 1.f, 7.f));
    qi[j >> 2] |= (iq & 255) << ((j & 3) * 8);
    unsigned f8 = f2fp8(s * fminf(r, 6.f) * 0.125f * sc);
    qf[j >> 2] |= (int)f8 << ((j & 3) * 8);
    short bb = f2bf(wv);
    if (j < 8) b0[j] = bb; else b1[j - 8] = bb;
  }
  *(i32x4*)(wqi + ((size_t)kg * N_DIM + n) * 16) = (i32x4){qi[0], qi[1], qi[2], qi[3]};
  *(i32x4*)(wdf + ((size_t)kg * N_DIM + n) * 16) = (i32x4){qf[0], qf[1], qf[2], qf[3]};
  *(bf16x8*)(wf + ((size_t)(2 * kg) * N_DIM + n) * 8) = b0;
  *(bf16x8*)(wf + ((size_t)(2 * kg + 1) * N_DIM + n) * 8) = b1;
}

// ============ kernel S: q0 (i8, exact sign) + q1 (MX-fp8 K=64, exact s2) ============
// 128x128 tile, BK=64, 4 waves 2x2, per-wave 64x64 via 32x32 frags.
// LDS/buf 32KB: [0,8K) A_i8 [kg16l:4][row:128]x16B | [8K,16K) A_f8 [kg16l:4][row:128]x16B
//               [16K,24K) B_i8 [kg16l:4][col:128]x16B | [24K,32K) B_f8 same
// dbuf 64KB -> 2 blocks/CU. Writes: sel bitmask + masked gelu(s2+db) into out.
#define S_BUF 32768
__global__ __launch_bounds__(256, 2) void sel_kernel(
    const signed char* __restrict__ aqi, const unsigned char* __restrict__ adf,
    const signed char* __restrict__ wqi, const unsigned char* __restrict__ wdf,
    const float* __restrict__ bias, unsigned int* __restrict__ bmask,
    float* __restrict__ out) {
  extern __shared__ char lds[];
  const int tid = threadIdx.x;
  const int wid = tid >> 6;
  const int lane = tid & 63;

  int bid = blockIdx.x;
  bid = (bid & 7) * 256 + (bid >> 3);      // XCD swizzle, 2048 blocks
  const int bm0 = (bid >> 5) * 128;
  const int bn0 = (bid & 31) * 128;

  const int wr = wid >> 1, wc = wid & 1;
  const int h = lane >> 5, l31 = lane & 31;
  const int ra = wr * 64 + l31;
  const int rb = wc * 64 + l31;

  i32x16 acc0[2][2];
  f32x16 acc1[2][2];
  const i32x16 zi = {0, 0, 0, 0, 0, 0, 0, 0, 0, 0, 0, 0, 0, 0, 0, 0};
  const f32x16 zf = {0, 0, 0, 0, 0, 0, 0, 0, 0, 0, 0, 0, 0, 0, 0, 0};
#pragma unroll
  for (int mf = 0; mf < 2; ++mf)
#pragma unroll
    for (int nf = 0; nf < 2; ++nf) { acc0[mf][nf] = zi; acc1[mf][nf] = zf; }

  // staging: 32 units x 1KB per buffer, 8 per wave -> vmcnt(8)
  const char* gb[8]; int lo[8]; int gs[8];
#pragma unroll
  for (int i = 0; i < 8; ++i) {
    int u = wid * 8 + i;
    lo[i] = u * 1024 + lane * 16;
    if (u < 8) {         // A_i8: kg16l = u>>1, rowhalf = u&1
      gb[i] = (const char*)aqi + ((size_t)(u >> 1) * M_DIM + bm0 + (u & 1) * 64 + lane) * 16;
      gs[i] = 4 * M_DIM * 16;
    } else if (u < 16) { // A_f8
      int v = u - 8;
      gb[i] = (const char*)adf + ((size_t)(v >> 1) * M_DIM + bm0 + (v & 1) * 64 + lane) * 16;
      gs[i] = 4 * M_DIM * 16;
    } else if (u < 24) { // B_i8
      int v = u - 16;
      gb[i] = (const char*)wqi + ((size_t)(v >> 1) * N_DIM + bn0 + (v & 1) * 64 + lane) * 16;
      gs[i] = 4 * N_DIM * 16;
    } else {             // B_f8
      int v = u - 24;
      gb[i] = (const char*)wdf + ((size_t)(v >> 1) * N_DIM + bn0 + (v & 1) * 64 + lane) * 16;
      gs[i] = 4 * N_DIM * 16;
    }
  }

#pragma unroll
  for (int i = 0; i < 8; ++i) gload16(gb[i], lds + lo[i]);  // tile 0 -> buf0

  for (int t = 0; t < 16; ++t) {
    const char* Bb = lds + (t & 1) * S_BUF;
    if (t < 15) {
      char* nb = lds + ((t + 1) & 1) * S_BUF;
#pragma unroll
      for (int i = 0; i < 8; ++i) gload16(gb[i] + (size_t)(t + 1) * gs[i], nb + lo[i]);
      asm volatile("s_waitcnt vmcnt(8)" ::: "memory");
    } else {
      asm volatile("s_waitcnt vmcnt(0)" ::: "memory");
    }
    __builtin_amdgcn_s_barrier();
    __builtin_amdgcn_sched_barrier(0);

    __builtin_amdgcn_s_setprio(1);
    // ---- q0: i8 sign GEMM, 2 kk-steps of K=32 ----
#pragma unroll
    for (int kk = 0; kk < 2; ++kk) {
      i32x4 a0[2], b0[2];
#pragma unroll
      for (int mf = 0; mf < 2; ++mf)
        a0[mf] = *(const i32x4*)(Bb + ((kk * 2 + h) * 128 + ra + mf * 32) * 16);
#pragma unroll
      for (int nf = 0; nf < 2; ++nf)
        b0[nf] = *(const i32x4*)(Bb + 16384 + ((kk * 2 + h) * 128 + rb + nf * 32) * 16);
#pragma unroll
      for (int mf = 0; mf < 2; ++mf)
#pragma unroll
        for (int nf = 0; nf < 2; ++nf)
          acc0[mf][nf] =
              __builtin_amdgcn_mfma_i32_32x32x32_i8(a0[mf], b0[nf], acc0[mf][nf], 0, 0, 0);
    }
    // ---- q1: MX-fp8 K=64 GEMM with unit scales (exact dequantized values) ----
    {
      i32x8 a1[2], b1[2];
#pragma unroll
      for (int mf = 0; mf < 2; ++mf) {
        i32x4 plo = *(const i32x4*)(Bb + 8192 + ((h * 2 + 0) * 128 + ra + mf * 32) * 16);
        i32x4 phi = *(const i32x4*)(Bb + 8192 + ((h * 2 + 1) * 128 + ra + mf * 32) * 16);
#pragma unroll
        for (int j = 0; j < 4; ++j) { a1[mf][j] = plo[j]; a1[mf][4 + j] = phi[j]; }
      }
#pragma unroll
      for (int nf = 0; nf < 2; ++nf) {
        i32x4 plo = *(const i32x4*)(Bb + 24576 + ((h * 2 + 0) * 128 + rb + nf * 32) * 16);
        i32x4 phi = *(const i32x4*)(Bb + 24576 + ((h * 2 + 1) * 128 + rb + nf * 32) * 16);
#pragma unroll
        for (int j = 0; j < 4; ++j) { b1[nf][j] = plo[j]; b1[nf][4 + j] = phi[j]; }
      }
#pragma unroll
      for (int mf = 0; mf < 2; ++mf)
#pragma unroll
        for (int nf = 0; nf < 2; ++nf)
          acc1[mf][nf] = __builtin_amdgcn_mfma_scale_f32_32x32x64_f8f6f4(
              a1[mf], b1[nf], acc1[mf][nf], 0, 0, 0, 0x7f7f7f7f, 0, 0x7f7f7f7f);
    }
    __builtin_amdgcn_s_setprio(0);
    asm volatile("s_waitcnt lgkmcnt(0)" ::: "memory");
    __builtin_amdgcn_sched_barrier(0);
    __builtin_amdgcn_s_barrier();
  }

  // ---- epilogue: sel bitmask + masked gelu(s2+db) store ----
#pragma unroll
  for (int nf = 0; nf < 2; ++nf) {
    const int col = bn0 + rb + nf * 32;
    const int cw = col >> 5;  // uniform per half-wave group (cols aligned to 32)
    const float bv = bias[col];
    const float sb = (bv > 0.f) ? 1.f : ((bv < 0.f) ? -1.f : 0.f);
    const float db = sb * fminf(rintf(fabsf(bv)), 6.f);
#pragma unroll
    for (int mf = 0; mf < 2; ++mf) {
#pragma unroll
      for (int r = 0; r < 16; ++r) {
        const int row0 = bm0 + wr * 64 + mf * 32 + (r & 3) + 8 * (r >> 2);
        const int row = row0 + 4 * h;
        bool sel = acc0[mf][nf][r] < 0;
        unsigned long long b = __ballot((int)sel);
        if (lane == 0) bmask[(size_t)row0 * 128 + cw] = (unsigned int)b;
        if (lane == 32) bmask[(size_t)(row0 + 4) * 128 + cw] = (unsigned int)(b >> 32);
        if (sel) out[(size_t)row * N_DIM + col] = gelu_f(acc1[mf][nf][r] + db);
      }
    }
  }
}

// ============ kernel F: q2 (bf16 full GEMM) + masked gelu store ============
// 128(M) x 256(N) tile, BK=32, 4 waves 1m x 4n, per-wave 128x64 (mf=4, nf=2).
// LDS/buf 24KB: [0,8K) A [kg8:4][row:128]x16B | [8K,24K) B [kg8:4][col:256]x16B
// dbuf 48KB -> 2 blocks/CU.
#define F_BUF 24576
__global__ __launch_bounds__(256, 2) void full_kernel(
    const short* __restrict__ af, const short* __restrict__ wf,
    const float* __restrict__ bias, const unsigned int* __restrict__ bmask,
    float* __restrict__ out) {
  extern __shared__ char lds[];
  const int tid = threadIdx.x;
  const int wid = tid >> 6;
  const int lane = tid & 63;

  int bid = blockIdx.x;
  bid = (bid & 7) * 128 + (bid >> 3);      // XCD swizzle, 1024 blocks
  const int bm0 = (bid >> 4) * 128;
  const int bn0 = (bid & 15) * 256;

  const int h = lane >> 5, l31 = lane & 31;

  f32x16 acc[4][2];
  const f32x16 zf = {0, 0, 0, 0, 0, 0, 0, 0, 0, 0, 0, 0, 0, 0, 0, 0};
#pragma unroll
  for (int mf = 0; mf < 4; ++mf)
#pragma unroll
    for (int nf = 0; nf < 2; ++nf) acc[mf][nf] = zf;

  // staging: 24 units x 1KB per buffer, 6 per wave -> vmcnt(6)
  const char* gb[6]; int lo[6]; int gs[6];
#pragma unroll
  for (int i = 0; i < 6; ++i) {
    int u = wid * 6 + i;
    lo[i] = u * 1024 + lane * 16;
    if (u < 8) {         // A: kg8 = u>>1, rowhalf = u&1
      gb[i] = (const char*)af + ((size_t)(u >> 1) * M_DIM + bm0 + (u & 1) * 64 + lane) * 16;
      gs[i] = 4 * M_DIM * 16;
    } else {             // B: v = u-8, kg8 = v>>2, colq = v&3
      int v = u - 8;
      gb[i] = (const char*)wf + ((size_t)(v >> 2) * N_DIM + bn0 + (v & 3) * 64 + lane) * 16;
      gs[i] = 4 * N_DIM * 16;
    }
  }

#pragma unroll
  for (int i = 0; i < 6; ++i) gload16(gb[i], lds + lo[i]);  // tile 0 -> buf0

  for (int t = 0; t < 32; ++t) {
    const char* Bb = lds + (t & 1) * F_BUF;
    if (t < 31) {
      char* nb = lds + ((t + 1) & 1) * F_BUF;
#pragma unroll
      for (int i = 0; i < 6; ++i) gload16(gb[i] + (size_t)(t + 1) * gs[i], nb + lo[i]);
      asm volatile("s_waitcnt vmcnt(6)" ::: "memory");
    } else {
      asm volatile("s_waitcnt vmcnt(0)" ::: "memory");
    }
    __builtin_amdgcn_s_barrier();
    __builtin_amdgcn_sched_barrier(0);

    __builtin_amdgcn_s_setprio(1);
#pragma unroll
    for (int kk = 0; kk < 2; ++kk) {
      bf16x8 a2[4], b2[2];
#pragma unroll
      for (int mf = 0; mf < 4; ++mf)
        a2[mf] = *(const bf16x8*)(Bb + ((kk * 2 + h) * 128 + mf * 32 + l31) * 16);
#pragma unroll
      for (int nf = 0; nf < 2; ++nf)
        b2[nf] = *(const bf16x8*)(Bb + 8192 +
                                  ((kk * 2 + h) * 256 + wid * 64 + nf * 32 + l31) * 16);
#pragma unroll
      for (int mf = 0; mf < 4; ++mf)
#pragma unroll
        for (int nf = 0; nf < 2; ++nf)
          acc[mf][nf] =
              __builtin_amdgcn_mfma_f32_32x32x16_bf16(a2[mf], b2[nf], acc[mf][nf], 0, 0, 0);
    }
    __builtin_amdgcn_s_setprio(0);
    asm volatile("s_waitcnt lgkmcnt(0)" ::: "memory");
    __builtin_amdgcn_sched_barrier(0);
    __builtin_amdgcn_s_barrier();
  }

  // ---- epilogue: store gelu(full+bias) where NOT selected ----
#pragma unroll
  for (int nf = 0; nf < 2; ++nf) {
    const int col = bn0 + wid * 64 + nf * 32 + l31;
    const int cw = col >> 5;
    const float bv = bias[col];
#pragma unroll
    for (int mf = 0; mf < 4; ++mf) {
#pragma unroll
      for (int r = 0; r < 16; ++r) {
        const int row = bm0 + mf * 32 + (r & 3) + 8 * (r >> 2) + 4 * h;
        unsigned int wsel = bmask[(size_t)row * 128 + cw];
        if (!((wsel >> (col & 31)) & 1u))
          out[(size_t)row * N_DIM + col] = gelu_f(acc[mf][nf][r] + bv);
      }
    }
  }
}

extern "C" void kernel_launch(void* const* d_in, const int* in_sizes, int n_in,
                              void* d_out, int out_size, void* d_ws, size_t ws_size,
                              hipStream_t stream) {
  const float* inp = (const float*)d_in[0];
  const float* w = (const float*)d_in[1];
  const float* bias = (const float*)d_in[2];
  float* out = (float*)d_out;

  // workspace: af 16.8 | wf 8.4 | aqi 8.4 | adf 8.4 | wqi 4.2 | wdf 4.2 | bmask 4.2 | mw (MB)
  char* p = (char*)d_ws;
  short* af = (short*)p;                  p += (size_t)M_DIM * K_DIM * 2;
  short* wf = (short*)p;                  p += (size_t)K_DIM * N_DIM * 2;
  signed char* aqi = (signed char*)p;     p += (size_t)M_DIM * K_DIM;
  unsigned char* adf = (unsigned char*)p; p += (size_t)M_DIM * K_DIM;
  signed char* wqi = (signed char*)p;     p += (size_t)K_DIM * N_DIM;
  unsigned char* wdf = (unsigned char*)p; p += (size_t)K_DIM * N_DIM;
  unsigned int* bmask = (unsigned int*)p; p += (size_t)M_DIM * N_DIM / 8;
  float* mw = (float*)p;

  hipFuncSetAttribute((const void*)sel_kernel,
                      hipFuncAttributeMaxDynamicSharedMemorySize, 2 * S_BUF);
  hipFuncSetAttribute((const void*)full_kernel,
                      hipFuncAttributeMaxDynamicSharedMemorySize, 2 * F_BUF);

  rowmax_kernel<<<K_DIM / 4, 256, 0, stream>>>(w, mw);
  prep_a_kernel<<<(M_DIM * K_DIM / 16) / 256, 256, 0, stream>>>(inp, aqi, adf, af);
  prep_w_kernel<<<(K_DIM * N_DIM / 16) / 256, 256, 0, stream>>>(w, mw, wqi, wdf, wf);
  sel_kernel<<<(M_DIM / 128) * (N_DIM / 128), 256, 2 * S_BUF, stream>>>(
      aqi, adf, wqi, wdf, bias, bmask, out);
  full_kernel<<<(M_DIM / 128) * (N_DIM / 256), 256, 2 * F_BUF, stream>>>(
      af, wf, bias, bmask, out);
}

// Round 11
// 225.197 us; speedup vs baseline: 1.5102x; 1.5102x over previous
//
#include <hip/hip_runtime.h>
#include <hip/hip_bf16.h>

// Problem shape: M = B*S = 8192, K = NX = 1024, N = NF = 4096
#define M_DIM 8192
#define K_DIM 1024
#define N_DIM 4096

typedef __attribute__((ext_vector_type(8))) short bf16x8;
typedef __attribute__((ext_vector_type(4))) int i32x4;
typedef __attribute__((ext_vector_type(8))) int i32x8;
typedef __attribute__((ext_vector_type(16))) int i32x16;
typedef __attribute__((ext_vector_type(16))) float f32x16;

__device__ __forceinline__ short f2bf(float f) {
  unsigned u = __builtin_bit_cast(unsigned, f);
  u = (u + 0x7fffu + ((u >> 16) & 1u)) >> 16;
  return (short)u;
}

// f32 -> OCP e4m3fn, exact for our value set (small ints x 2^e)
__device__ __forceinline__ unsigned f2fp8(float v) {
  unsigned b = __builtin_bit_cast(unsigned, v);
  unsigned sg = (b >> 24) & 0x80u;
  unsigned ab = b & 0x7fffffffu;
  if (ab == 0) return sg;
  int e = (int)(ab >> 23) - 127;
  unsigned m3 = (ab >> 20) & 7u;
  if (e >= -6) return sg | (unsigned)((e + 7) << 3) | m3;
  return sg | ((8u + m3) >> (-6 - e));  // subnormal (exact for our values)
}

__device__ __forceinline__ float gelu_f(float x) {
  float u = 0.7978845608028654f * (x + 0.044715f * x * x * x);
  float e = __expf(2.0f * u);
  float t = 1.0f - 2.0f / (e + 1.0f);
  return 0.5f * x * (1.0f + t);
}

__device__ __forceinline__ void gload16(const void* g, void* l) {
  __builtin_amdgcn_global_load_lds((const __attribute__((address_space(1))) void*)g,
                                   (__attribute__((address_space(3))) void*)l, 16, 0, 0);
}

// ---------------- per-k power-of-2 weight scale ----------------
__global__ void rowmax_kernel(const float* __restrict__ w, float* __restrict__ mw) {
  int row = blockIdx.x * 4 + (threadIdx.x >> 6);
  int lane = threadIdx.x & 63;
  const float4* rp = (const float4*)(w + (size_t)row * N_DIM);
  float m = 0.0f;
#pragma unroll
  for (int it = 0; it < 16; ++it) {
    float4 v = rp[it * 64 + lane];
    m = fmaxf(m, fmaxf(fmaxf(fabsf(v.x), fabsf(v.y)), fmaxf(fabsf(v.z), fabsf(v.w))));
  }
#pragma unroll
  for (int off = 32; off > 0; off >>= 1) m = fmaxf(m, __shfl_xor(m, off, 64));
  if (lane == 0) mw[row] = exp2f(rintf(log2f(m)));
}

// ---------------- prep A: one thread per (kg16, m); 16 k-values ----------------
// aqi: [kg16:64][m]x16B i8 (in_q) | adf: [kg16:64][m]x16B fp8 (deq(in_q)) | af: [kg8:128][m]x16B bf16
__global__ void prep_a_kernel(const float* __restrict__ inp, signed char* __restrict__ aqi,
                              unsigned char* __restrict__ adf, short* __restrict__ af) {
  int c = blockIdx.x * 256 + threadIdx.x;
  int kg = c >> 13, m = c & 8191;
  const float4* src = (const float4*)(inp + (size_t)m * K_DIM + kg * 16);
  float xs[16];
#pragma unroll
  for (int v = 0; v < 4; ++v) {
    float4 t = src[v];
    xs[v * 4 + 0] = t.x; xs[v * 4 + 1] = t.y; xs[v * 4 + 2] = t.z; xs[v * 4 + 3] = t.w;
  }
  int qi[4] = {0, 0, 0, 0};
  int qf[4] = {0, 0, 0, 0};
  bf16x8 b0, b1;
#pragma unroll
  for (int j = 0; j < 16; ++j) {
    float x = xs[j];
    float s = (x > 0.f) ? 1.f : ((x < 0.f) ? -1.f : 0.f);
    float r = rintf(fabsf(x));
    int iq = (int)(s * fminf(r + 1.f, 7.f));
    qi[j >> 2] |= (iq & 255) << ((j & 3) * 8);
    unsigned f8 = f2fp8(s * fminf(r, 6.f));
    qf[j >> 2] |= (int)f8 << ((j & 3) * 8);
    short bb = f2bf(x);
    if (j < 8) b0[j] = bb; else b1[j - 8] = bb;
  }
  *(i32x4*)(aqi + ((size_t)kg * M_DIM + m) * 16) = (i32x4){qi[0], qi[1], qi[2], qi[3]};
  *(i32x4*)(adf + ((size_t)kg * M_DIM + m) * 16) = (i32x4){qf[0], qf[1], qf[2], qf[3]};
  *(bf16x8*)(af + ((size_t)(2 * kg) * M_DIM + m) * 8) = b0;
  *(bf16x8*)(af + ((size_t)(2 * kg + 1) * M_DIM + m) * 8) = b1;
}

// ---------------- prep W: one thread per (kg16, n) ----------------
__global__ void prep_w_kernel(const float* __restrict__ w, const float* __restrict__ mw,
                              signed char* __restrict__ wqi, unsigned char* __restrict__ wdf,
                              short* __restrict__ wf) {
  int c = blockIdx.x * 256 + threadIdx.x;
  int kg = c >> 12, n = c & 4095;
  int qi[4] = {0, 0, 0, 0};
  int qf[4] = {0, 0, 0, 0};
  bf16x8 b0, b1;
#pragma unroll
  for (int j = 0; j < 16; ++j) {
    float wv = w[(size_t)(kg * 16 + j) * N_DIM + n];
    float sc = mw[kg * 16 + j];
    float s = (wv > 0.f) ? 1.f : ((wv < 0.f) ? -1.f : 0.f);
    float r = rintf(fabsf(wv) * (8.0f / sc));
    int iq = (int)(s * fminf(r + 1.f, 7.f));
    qi[j >> 2] |= (iq & 255) << ((j & 3) * 8);
    unsigned f8 = f2fp8(s * fminf(r, 6.f) * 0.125f * sc);
    qf[j >> 2] |= (int)f8 << ((j & 3) * 8);
    short bb = f2bf(wv);
    if (j < 8) b0[j] = bb; else b1[j - 8] = bb;
  }
  *(i32x4*)(wqi + ((size_t)kg * N_DIM + n) * 16) = (i32x4){qi[0], qi[1], qi[2], qi[3]};
  *(i32x4*)(wdf + ((size_t)kg * N_DIM + n) * 16) = (i32x4){qf[0], qf[1], qf[2], qf[3]};
  *(bf16x8*)(wf + ((size_t)(2 * kg) * N_DIM + n) * 8) = b0;
  *(bf16x8*)(wf + ((size_t)(2 * kg + 1) * N_DIM + n) * 8) = b1;
}

// ============ kernel F (runs FIRST): q2 bf16 full GEMM, unconditional gelu store ============
// 128(M) x 256(N) tile, BK=32, 4 waves 1m x 4n, per-wave 128x64 (mf=4, nf=2).
// LDS/buf 24KB: [0,8K) A [kg8:4][row:128]x16B | [8K,24K) B [kg8:4][col:256]x16B
// dbuf 48KB -> 2 blocks/CU. Coalesced full-line stores: no fetch-for-write, no mask reads.
#define F_BUF 24576
__global__ __launch_bounds__(256, 2) void full_kernel(
    const short* __restrict__ af, const short* __restrict__ wf,
    const float* __restrict__ bias, float* __restrict__ out) {
  extern __shared__ char lds[];
  const int tid = threadIdx.x;
  const int wid = tid >> 6;
  const int lane = tid & 63;

  int bid = blockIdx.x;
  bid = (bid & 7) * 128 + (bid >> 3);      // XCD swizzle, 1024 blocks
  const int bm0 = (bid >> 4) * 128;
  const int bn0 = (bid & 15) * 256;

  const int h = lane >> 5, l31 = lane & 31;

  f32x16 acc[4][2];
  const f32x16 zf = {0, 0, 0, 0, 0, 0, 0, 0, 0, 0, 0, 0, 0, 0, 0, 0};
#pragma unroll
  for (int mf = 0; mf < 4; ++mf)
#pragma unroll
    for (int nf = 0; nf < 2; ++nf) acc[mf][nf] = zf;

  // staging: 24 units x 1KB per buffer, 6 per wave -> vmcnt(6)
  const char* gb[6]; int lo[6]; int gs[6];
#pragma unroll
  for (int i = 0; i < 6; ++i) {
    int u = wid * 6 + i;
    lo[i] = u * 1024 + lane * 16;
    if (u < 8) {         // A: kg8 = u>>1, rowhalf = u&1
      gb[i] = (const char*)af + ((size_t)(u >> 1) * M_DIM + bm0 + (u & 1) * 64 + lane) * 16;
      gs[i] = 4 * M_DIM * 16;
    } else {             // B: v = u-8, kg8 = v>>2, colq = v&3
      int v = u - 8;
      gb[i] = (const char*)wf + ((size_t)(v >> 2) * N_DIM + bn0 + (v & 3) * 64 + lane) * 16;
      gs[i] = 4 * N_DIM * 16;
    }
  }

#pragma unroll
  for (int i = 0; i < 6; ++i) gload16(gb[i], lds + lo[i]);  // tile 0 -> buf0

#pragma unroll 1
  for (int t = 0; t < 32; ++t) {
    const char* Bb = lds + (t & 1) * F_BUF;
    if (t < 31) {
      char* nb = lds + ((t + 1) & 1) * F_BUF;
#pragma unroll
      for (int i = 0; i < 6; ++i) gload16(gb[i] + (size_t)(t + 1) * gs[i], nb + lo[i]);
      asm volatile("s_waitcnt vmcnt(6)" ::: "memory");
    } else {
      asm volatile("s_waitcnt vmcnt(0)" ::: "memory");
    }
    __builtin_amdgcn_s_barrier();
    __builtin_amdgcn_sched_barrier(0);

    __builtin_amdgcn_s_setprio(1);
#pragma unroll
    for (int kk = 0; kk < 2; ++kk) {
      bf16x8 a2[4], b2[2];
#pragma unroll
      for (int mf = 0; mf < 4; ++mf)
        a2[mf] = *(const bf16x8*)(Bb + ((kk * 2 + h) * 128 + mf * 32 + l31) * 16);
#pragma unroll
      for (int nf = 0; nf < 2; ++nf)
        b2[nf] = *(const bf16x8*)(Bb + 8192 +
                                  ((kk * 2 + h) * 256 + wid * 64 + nf * 32 + l31) * 16);
#pragma unroll
      for (int mf = 0; mf < 4; ++mf)
#pragma unroll
        for (int nf = 0; nf < 2; ++nf)
          acc[mf][nf] =
              __builtin_amdgcn_mfma_f32_32x32x16_bf16(a2[mf], b2[nf], acc[mf][nf], 0, 0, 0);
    }
    __builtin_amdgcn_s_setprio(0);
    asm volatile("s_waitcnt lgkmcnt(0)" ::: "memory");
    __builtin_amdgcn_sched_barrier(0);
    __builtin_amdgcn_s_barrier();
  }

  // ---- epilogue: UNCONDITIONAL gelu(full+bias) store (coalesced, full lines) ----
#pragma unroll
  for (int nf = 0; nf < 2; ++nf) {
    const int col = bn0 + wid * 64 + nf * 32 + l31;
    const float bv = bias[col];
#pragma unroll
    for (int mf = 0; mf < 4; ++mf) {
#pragma unroll
      for (int r = 0; r < 16; ++r) {
        const int row = bm0 + mf * 32 + (r & 3) + 8 * (r >> 2) + 4 * h;
        out[(size_t)row * N_DIM + col] = gelu_f(acc[mf][nf][r] + bv);
      }
    }
  }
}

// ============ kernel S (runs SECOND): q0 (i8 sign) + q1 (MX-fp8 K=64), overwrite ============
// 128x128 tile, BK=64, 4 waves 2x2, per-wave 64x64 via 32x32 frags.
// LDS/buf 32KB: [0,8K) A_i8 | [8K,16K) A_f8 | [16K,24K) B_i8 | [24K,32K) B_f8
// dbuf 64KB -> 2 blocks/CU. Overwrites out where s1 < 0 with gelu(s2+db).
#define S_BUF 32768
__global__ __launch_bounds__(256, 2) void sel_kernel(
    const signed char* __restrict__ aqi, const unsigned char* __restrict__ adf,
    const signed char* __restrict__ wqi, const unsigned char* __restrict__ wdf,
    const float* __restrict__ bias, float* __restrict__ out) {
  extern __shared__ char lds[];
  const int tid = threadIdx.x;
  const int wid = tid >> 6;
  const int lane = tid & 63;

  int bid = blockIdx.x;
  bid = (bid & 7) * 256 + (bid >> 3);      // XCD swizzle, 2048 blocks
  const int bm0 = (bid >> 5) * 128;
  const int bn0 = (bid & 31) * 128;

  const int wr = wid >> 1, wc = wid & 1;
  const int h = lane >> 5, l31 = lane & 31;
  const int ra = wr * 64 + l31;
  const int rb = wc * 64 + l31;

  i32x16 acc0[2][2];
  f32x16 acc1[2][2];
  const i32x16 zi = {0, 0, 0, 0, 0, 0, 0, 0, 0, 0, 0, 0, 0, 0, 0, 0};
  const f32x16 zf = {0, 0, 0, 0, 0, 0, 0, 0, 0, 0, 0, 0, 0, 0, 0, 0};
#pragma unroll
  for (int mf = 0; mf < 2; ++mf)
#pragma unroll
    for (int nf = 0; nf < 2; ++nf) { acc0[mf][nf] = zi; acc1[mf][nf] = zf; }

  // staging: 32 units x 1KB per buffer, 8 per wave -> vmcnt(8)
  const char* gb[8]; int lo[8]; int gs[8];
#pragma unroll
  for (int i = 0; i < 8; ++i) {
    int u = wid * 8 + i;
    lo[i] = u * 1024 + lane * 16;
    if (u < 8) {         // A_i8: kg16l = u>>1, rowhalf = u&1
      gb[i] = (const char*)aqi + ((size_t)(u >> 1) * M_DIM + bm0 + (u & 1) * 64 + lane) * 16;
      gs[i] = 4 * M_DIM * 16;
    } else if (u < 16) { // A_f8
      int v = u - 8;
      gb[i] = (const char*)adf + ((size_t)(v >> 1) * M_DIM + bm0 + (v & 1) * 64 + lane) * 16;
      gs[i] = 4 * M_DIM * 16;
    } else if (u < 24) { // B_i8
      int v = u - 16;
      gb[i] = (const char*)wqi + ((size_t)(v >> 1) * N_DIM + bn0 + (v & 1) * 64 + lane) * 16;
      gs[i] = 4 * N_DIM * 16;
    } else {             // B_f8
      int v = u - 24;
      gb[i] = (const char*)wdf + ((size_t)(v >> 1) * N_DIM + bn0 + (v & 1) * 64 + lane) * 16;
      gs[i] = 4 * N_DIM * 16;
    }
  }

#pragma unroll
  for (int i = 0; i < 8; ++i) gload16(gb[i], lds + lo[i]);  // tile 0 -> buf0

#pragma unroll 1
  for (int t = 0; t < 16; ++t) {
    const char* Bb = lds + (t & 1) * S_BUF;
    if (t < 15) {
      char* nb = lds + ((t + 1) & 1) * S_BUF;
#pragma unroll
      for (int i = 0; i < 8; ++i) gload16(gb[i] + (size_t)(t + 1) * gs[i], nb + lo[i]);
      asm volatile("s_waitcnt vmcnt(8)" ::: "memory");
    } else {
      asm volatile("s_waitcnt vmcnt(0)" ::: "memory");
    }
    __builtin_amdgcn_s_barrier();
    __builtin_amdgcn_sched_barrier(0);

    __builtin_amdgcn_s_setprio(1);
    // ---- q0: i8 sign GEMM, 2 kk-steps of K=32 ----
#pragma unroll
    for (int kk = 0; kk < 2; ++kk) {
      i32x4 a0[2], b0[2];
#pragma unroll
      for (int mf = 0; mf < 2; ++mf)
        a0[mf] = *(const i32x4*)(Bb + ((kk * 2 + h) * 128 + ra + mf * 32) * 16);
#pragma unroll
      for (int nf = 0; nf < 2; ++nf)
        b0[nf] = *(const i32x4*)(Bb + 16384 + ((kk * 2 + h) * 128 + rb + nf * 32) * 16);
#pragma unroll
      for (int mf = 0; mf < 2; ++mf)
#pragma unroll
        for (int nf = 0; nf < 2; ++nf)
          acc0[mf][nf] =
              __builtin_amdgcn_mfma_i32_32x32x32_i8(a0[mf], b0[nf], acc0[mf][nf], 0, 0, 0);
    }
    // ---- q1: MX-fp8 K=64 GEMM with unit scales (exact dequantized values) ----
    {
      i32x8 a1[2], b1[2];
#pragma unroll
      for (int mf = 0; mf < 2; ++mf) {
        i32x4 plo = *(const i32x4*)(Bb + 8192 + ((h * 2 + 0) * 128 + ra + mf * 32) * 16);
        i32x4 phi = *(const i32x4*)(Bb + 8192 + ((h * 2 + 1) * 128 + ra + mf * 32) * 16);
#pragma unroll
        for (int j = 0; j < 4; ++j) { a1[mf][j] = plo[j]; a1[mf][4 + j] = phi[j]; }
      }
#pragma unroll
      for (int nf = 0; nf < 2; ++nf) {
        i32x4 plo = *(const i32x4*)(Bb + 24576 + ((h * 2 + 0) * 128 + rb + nf * 32) * 16);
        i32x4 phi = *(const i32x4*)(Bb + 24576 + ((h * 2 + 1) * 128 + rb + nf * 32) * 16);
#pragma unroll
        for (int j = 0; j < 4; ++j) { b1[nf][j] = plo[j]; b1[nf][4 + j] = phi[j]; }
      }
#pragma unroll
      for (int mf = 0; mf < 2; ++mf)
#pragma unroll
        for (int nf = 0; nf < 2; ++nf)
          acc1[mf][nf] = __builtin_amdgcn_mfma_scale_f32_32x32x64_f8f6f4(
              a1[mf], b1[nf], acc1[mf][nf], 0, 0, 0, 0x7f7f7f7f, 0, 0x7f7f7f7f);
    }
    __builtin_amdgcn_s_setprio(0);
    asm volatile("s_waitcnt lgkmcnt(0)" ::: "memory");
    __builtin_amdgcn_sched_barrier(0);
    __builtin_amdgcn_s_barrier();
  }

  // ---- epilogue: overwrite selected elements with gelu(s2 + deq-bias) ----
#pragma unroll
  for (int nf = 0; nf < 2; ++nf) {
    const int col = bn0 + rb + nf * 32;
    const float bv = bias[col];
    const float sb = (bv > 0.f) ? 1.f : ((bv < 0.f) ? -1.f : 0.f);
    const float db = sb * fminf(rintf(fabsf(bv)), 6.f);
#pragma unroll
    for (int mf = 0; mf < 2; ++mf) {
#pragma unroll
      for (int r = 0; r < 16; ++r) {
        const int row = bm0 + wr * 64 + mf * 32 + (r & 3) + 8 * (r >> 2) + 4 * h;
        if (acc0[mf][nf][r] < 0)
          out[(size_t)row * N_DIM + col] = gelu_f(acc1[mf][nf][r] + db);
      }
    }
  }
}

extern "C" void kernel_launch(void* const* d_in, const int* in_sizes, int n_in,
                              void* d_out, int out_size, void* d_ws, size_t ws_size,
                              hipStream_t stream) {
  const float* inp = (const float*)d_in[0];
  const float* w = (const float*)d_in[1];
  const float* bias = (const float*)d_in[2];
  float* out = (float*)d_out;

  // workspace: af 16.8 | wf 8.4 | aqi 8.4 | adf 8.4 | wqi 4.2 | wdf 4.2 | mw (MB)
  char* p = (char*)d_ws;
  short* af = (short*)p;                  p += (size_t)M_DIM * K_DIM * 2;
  short* wf = (short*)p;                  p += (size_t)K_DIM * N_DIM * 2;
  signed char* aqi = (signed char*)p;     p += (size_t)M_DIM * K_DIM;
  unsigned char* adf = (unsigned char*)p; p += (size_t)M_DIM * K_DIM;
  signed char* wqi = (signed char*)p;     p += (size_t)K_DIM * N_DIM;
  unsigned char* wdf = (unsigned char*)p; p += (size_t)K_DIM * N_DIM;
  float* mw = (float*)p;

  hipFuncSetAttribute((const void*)full_kernel,
                      hipFuncAttributeMaxDynamicSharedMemorySize, 2 * F_BUF);
  hipFuncSetAttribute((const void*)sel_kernel,
                      hipFuncAttributeMaxDynamicSharedMemorySize, 2 * S_BUF);

  rowmax_kernel<<<K_DIM / 4, 256, 0, stream>>>(w, mw);
  prep_a_kernel<<<(M_DIM * K_DIM / 16) / 256, 256, 0, stream>>>(inp, aqi, adf, af);
  prep_w_kernel<<<(K_DIM * N_DIM / 16) / 256, 256, 0, stream>>>(w, mw, wqi, wdf, wf);
  full_kernel<<<(M_DIM / 128) * (N_DIM / 256), 256, 2 * F_BUF, stream>>>(af, wf, bias, out);
  sel_kernel<<<(M_DIM / 128) * (N_DIM / 128), 256, 2 * S_BUF, stream>>>(
      aqi, adf, wqi, wdf, bias, out);
}